// Round 2
// baseline (114.370 us; speedup 1.0000x reference)
//
#include <hip/hip_runtime.h>

// Problem constants
#define B_       128
#define N_WAY    5
#define QUERY    15
#define NUM_SLOT 32
#define H_       256
#define NS       (B_ * N_WAY)            // 640 support samples
#define NQ       (B_ * N_WAY * QUERY)    // 9600 query samples
#define ROW      (NUM_SLOT * H_)         // 8192 floats per sample
#define SPB      (N_WAY * QUERY)         // 75 query samples per batch
#define NBLK_MAIN (NQ / 4)               // 2400 blocks, 4 samples each

__device__ __forceinline__ float wave_reduce(float v) {
    for (int m = 32; m > 0; m >>= 1) v += __shfl_xor(v, m, 64);
    return v;
}

// K1: scores[sample][slot] = mean over H; one wave per row (float4/lane), 4 waves/block
__global__ void k_scores(const float* __restrict__ out_f, float* __restrict__ scores) {
    int wid = threadIdx.x >> 6, lane = threadIdx.x & 63;
    int row = blockIdx.x * 4 + wid;                 // 0 .. NS*NUM_SLOT-1 (20480)
    const float4* p = (const float4*)(out_f + (size_t)row * H_);
    float4 v = p[lane];
    float s = wave_reduce(v.x + v.y + v.z + v.w);
    if (lane == 0) scores[row] = s * (1.0f / H_);
}

// K2: per-batch block: greedy select (LDS-staged scores, thread 0) + normalize the
// 5 selected support rows -> proto. Block 0 also zeroes the K3 accumulators.
__global__ void k_selproto(const float* __restrict__ scores, const float* __restrict__ out_f,
                           int* __restrict__ sel, float* __restrict__ proto,
                           float* __restrict__ acc) {
    int b = blockIdx.x;
    int t = threadIdx.x;
    __shared__ float sc[N_WAY * NUM_SLOT];
    __shared__ int ssel[N_WAY];
    if (t < N_WAY * NUM_SLOT) sc[t] = scores[b * N_WAY * NUM_SLOT + t];
    if (b == 0 && t < 3) ((unsigned*)acc)[t] = 0u;   // nll_sum, corr_sum, count
    __syncthreads();
    if (t == 0) {
        unsigned used = 0u;
        for (int j = 0; j < N_WAY; ++j) {
            float best = -INFINITY; int bi = 0;
            #pragma unroll
            for (int s = 0; s < NUM_SLOT; ++s) {
                bool ok = !((used >> s) & 1u);
                float v = sc[j * NUM_SLOT + s];
                if (ok && v > best) { best = v; bi = s; }  // strict > == stable argsort pick
            }
            used |= 1u << bi;
            ssel[j] = bi;
        }
        #pragma unroll
        for (int j = 0; j < N_WAY; ++j) sel[b * N_WAY + j] = ssel[j];
    }
    __syncthreads();
    int wid = t >> 6, lane = t & 63;
    for (int k = wid; k < N_WAY; k += 4) {
        int r = b * N_WAY + k;
        int slot = ssel[k];
        const float4* p = (const float4*)(out_f + (size_t)r * ROW + (size_t)slot * H_);
        float4 v = p[lane];
        float s2 = wave_reduce(v.x*v.x + v.y*v.y + v.z*v.z + v.w*v.w);
        float inv = 1.0f / fmaxf(sqrtf(s2), 1e-12f);
        ((float4*)(proto + (size_t)r * H_))[lane] =
            make_float4(v.x*inv, v.y*inv, v.z*inv, v.w*inv);
    }
}

// K3: per query-sample wave: 5x joint reduce (|q|^2, q.p, |p|^2) -> diffs,
// softmax-CE + argmin; block partial -> global atomics; last block finalizes.
__global__ void k_main(const float* __restrict__ out_f, const int* __restrict__ sel,
                       const float* __restrict__ proto, const int* __restrict__ labels_q,
                       const float* __restrict__ att_loss, float* __restrict__ acc,
                       float* __restrict__ out) {
    int wid = threadIdx.x >> 6, lane = threadIdx.x & 63;
    int id = blockIdx.x * 4 + wid;                  // 0..9599 exact
    int b = id / SPB;
    const float* qrow = out_f + (size_t)(NS + id) * ROW;

    float diffs[N_WAY];
    #pragma unroll
    for (int k = 0; k < N_WAY; ++k) {
        int slot = sel[b * N_WAY + k];
        float4 qv = ((const float4*)(qrow + (size_t)slot * H_))[lane];
        float4 pv = ((const float4*)(proto + (size_t)(b * N_WAY + k) * H_))[lane];
        float s2 = qv.x*qv.x + qv.y*qv.y + qv.z*qv.z + qv.w*qv.w;
        float dt = qv.x*pv.x + qv.y*pv.y + qv.z*pv.z + qv.w*pv.w;
        float p2 = pv.x*pv.x + pv.y*pv.y + pv.z*pv.z + pv.w*pv.w;
        for (int m = 32; m > 0; m >>= 1) {
            s2 += __shfl_xor(s2, m, 64);
            dt += __shfl_xor(dt, m, 64);
            p2 += __shfl_xor(p2, m, 64);
        }
        float inv = 1.0f / fmaxf(sqrtf(s2), 1e-12f);
        diffs[k] = s2 * inv * inv - 2.0f * dt * inv + p2;
    }

    __shared__ float s_n[4], s_c[4];
    if (lane == 0) {
        int l = labels_q[id];
        float mn = diffs[0]; int am = 0;
        #pragma unroll
        for (int k = 1; k < N_WAY; ++k)
            if (diffs[k] < mn) { mn = diffs[k]; am = k; }   // first min == argmax logits
        float se = 0.0f;
        #pragma unroll
        for (int k = 0; k < N_WAY; ++k) se += expf(mn - diffs[k]);
        s_n[wid] = diffs[l] - mn + logf(se);
        s_c[wid] = (am == l) ? 1.0f : 0.0f;
    }
    __syncthreads();
    if (threadIdx.x == 0) {
        float pn = s_n[0] + s_n[1] + s_n[2] + s_n[3];
        float pc = s_c[0] + s_c[1] + s_c[2] + s_c[3];
        atomicAdd(&acc[0], pn);
        atomicAdd(&acc[1], pc);
        __threadfence();
        unsigned old = atomicAdd((unsigned*)&acc[2], 1u);
        if (old == (unsigned)(gridDim.x - 1)) {
            float sn_ = atomicAdd(&acc[0], 0.0f);   // coherent read-back
            float sc_ = atomicAdd(&acc[1], 0.0f);
            out[0] = sn_ * (1.0f / NQ) + att_loss[0];   // LAMBDA = 1.0
            out[1] = sc_ * (1.0f / NQ);
        }
    }
}

extern "C" void kernel_launch(void* const* d_in, const int* in_sizes, int n_in,
                              void* d_out, int out_size, void* d_ws, size_t ws_size,
                              hipStream_t stream) {
    const float* out_f    = (const float*)d_in[0];
    // d_in[1] = labels_support (unused by reference)
    const int*   labels_q = (const int*)d_in[2];
    const float* att_loss = (const float*)d_in[3];
    // d_in[4] = mode (unused)
    float* out = (float*)d_out;

    // workspace layout (floats)
    float* ws     = (float*)d_ws;
    float* scores = ws;                      // 20480
    int*   sel    = (int*)(ws + 20480);      // 640
    float* proto  = ws + 21120;              // 163840
    float* acc    = ws + 184960;             // 3 (nll_sum, corr_sum, counter)

    k_scores  <<<(NS * NUM_SLOT) / 4, 256, 0, stream>>>(out_f, scores);
    k_selproto<<<B_, 256, 0, stream>>>(scores, out_f, sel, proto, acc);
    k_main    <<<NBLK_MAIN, 256, 0, stream>>>(out_f, sel, proto, labels_q, att_loss, acc, out);
}